// Round 5
// baseline (407.394 us; speedup 1.0000x reference)
//
#include <hip/hip_runtime.h>

#define IN_F 512
#define HID_F 256
#define LAT_F 128

typedef __bf16 bf16x8 __attribute__((ext_vector_type(8)));
typedef float floatx4 __attribute__((ext_vector_type(4)));

#define FIX_SCALE 1048576.0f   // 2^20 fixed-point for degree accumulation

__device__ __forceinline__ unsigned short f2bf(float f) {
    union { float f; unsigned u; } v; v.f = f;
    unsigned r = (v.u + 0x7fff + ((v.u >> 16) & 1)) >> 16;
    return (unsigned short)r;
}
__device__ __forceinline__ float bf2f(unsigned short h) {
    union { unsigned u; float f; } v; v.u = ((unsigned)h) << 16;
    return v.f;
}

// ---------------- fused prep: packed init + B in MFMA-fragment order ----------------
// Bf layout: frag f = ((wave*NKS + ks)*2 + jj), element (lane, j):
//   Bf[(f*64 + lane)*8 + j] = W[k][n],  n = wave*32 + jj*16 + (lane&15),
//                                        k = ks*32 + (lane>>4)*8 + j

__global__ void prep_all(const float* __restrict__ W1, const float* __restrict__ Wmu,
                         const float* __restrict__ Wlv, unsigned long long* __restrict__ packed,
                         unsigned short* __restrict__ Bf1, unsigned short* __restrict__ Bf2,
                         int N) {
    int t = blockIdx.x * 256 + threadIdx.x;
    if (t < N) packed[t] = (1ULL << 32) | (unsigned long long)(unsigned)FIX_SCALE;  // count=1, w=1.0
    if (t < HID_F * IN_F) {            // GEMM1 frags: 8 waves x 16 ks x 2 jj x 64 lanes x 8
        int j = t & 7, l = (t >> 3) & 63, jj = (t >> 9) & 1, ks = (t >> 10) & 15, w = t >> 14;
        int n = w * 32 + jj * 16 + (l & 15);
        int k = ks * 32 + (l >> 4) * 8 + j;
        Bf1[t] = f2bf(W1[(size_t)k * HID_F + n]);
    }
    if (t < HID_F * HID_F) {           // GEMM2 frags: 8 waves x 8 ks x 2 jj x 64 lanes x 8
        int j = t & 7, l = (t >> 3) & 63, jj = (t >> 9) & 1, ks = (t >> 10) & 7, w = t >> 13;
        int n = w * 32 + jj * 16 + (l & 15);
        int k = ks * 32 + (l >> 4) * 8 + j;
        float v = (n < 128) ? Wmu[(size_t)k * LAT_F + n] : Wlv[(size_t)k * LAT_F + (n - 128)];
        Bf2[t] = f2bf(v);
    }
}

// ---------------- degree pass: ONE u64 atomic per edge; returns CSR slot ----------------

__global__ void edge_deg(const int* __restrict__ ei, const float* __restrict__ attr,
                         unsigned long long* __restrict__ packed, int* __restrict__ slot, int E) {
    int e = blockIdx.x * 256 + threadIdx.x;
    if (e < E) {
        int d = ei[E + e];
        unsigned fw = __float2uint_rn(attr[e] * FIX_SCALE);
        unsigned long long old = atomicAdd(&packed[d], (1ULL << 32) | (unsigned long long)fw);
        slot[e] = (int)(old >> 32);    // count before increment (self-loop holds slot 0)
    }
}

// ---------------- scan pass 1 (fused with dis computation) ----------------

__global__ void scan_blocks(const unsigned long long* __restrict__ packed,
                            float* __restrict__ dis, int* __restrict__ excl,
                            int* __restrict__ blockSums, int N) {
    __shared__ int sdata[256];
    int tid = threadIdx.x;
    int base = blockIdx.x * 1024 + tid * 4;
    int v[4]; int sum = 0;
#pragma unroll
    for (int j = 0; j < 4; ++j) {
        int c = 0;
        if (base + j < N) {
            unsigned long long p = packed[base + j];
            c = (int)(p >> 32);
            float dg = (float)(unsigned)(p & 0xffffffffu) * (1.0f / FIX_SCALE);
            dis[base + j] = dg > 0.f ? rsqrtf(fmaxf(dg, 1e-12f)) : 0.f;
        }
        v[j] = c; sum += c;
    }
    sdata[tid] = sum;
    __syncthreads();
    for (int off = 1; off < 256; off <<= 1) {
        int t = (tid >= off) ? sdata[tid - off] : 0;
        __syncthreads();
        sdata[tid] += t;
        __syncthreads();
    }
    if (tid == 255) blockSums[blockIdx.x] = sdata[255];
    int run = sdata[tid] - sum;
#pragma unroll
    for (int j = 0; j < 4; ++j) { if (base + j < N) excl[base + j] = run; run += v[j]; }
}

__global__ void scan_sums(int* blockSums, int NB) {
    __shared__ int s[64];
    int tid = threadIdx.x;
    int v = (tid < NB) ? blockSums[tid] : 0;
    s[tid] = v;
    __syncthreads();
    for (int off = 1; off < 64; off <<= 1) {
        int t = (tid >= off) ? s[tid - off] : 0;
        __syncthreads();
        s[tid] += t;
        __syncthreads();
    }
    if (tid < NB) blockSums[tid] = s[tid] - v;
}

__global__ void scan_add(int* row_ptr, const int* __restrict__ blockSums, int N, int total) {
    int tid = threadIdx.x;
    int base = blockIdx.x * 1024 + tid * 4;
    int add = blockSums[blockIdx.x];
#pragma unroll
    for (int j = 0; j < 4; ++j) if (base + j < N) row_ptr[base + j] += add;
    if (blockIdx.x == 0 && tid == 0) row_ptr[N] = total;
}

// ---------------- CSR fill (NO atomics — slots precomputed) ----------------

__global__ void fill_csr(const int* __restrict__ ei, const float* __restrict__ attr,
                         const int* __restrict__ slot, const float* __restrict__ dis,
                         const int* __restrict__ row_ptr,
                         int* __restrict__ col, float* __restrict__ val, int E, int N) {
    int e = blockIdx.x * 256 + threadIdx.x;
    if (e >= E + N) return;
    int s, d, sl; float w;
    if (e < E) { s = ei[e]; d = ei[E + e]; w = attr[e]; sl = slot[e]; }
    else       { s = d = e - E; w = 1.0f; sl = 0; }
    int pos = row_ptr[d] + sl;
    col[pos] = s;
    val[pos] = dis[s] * w * dis[d];
}

// ---------------- B-in-registers MFMA GEMM (structure from round 3; grid 512 now) ----------------

template <bool ABF16, int KK>
__global__ __launch_bounds__(512, 2) void gemm_breg(const void* __restrict__ Avoid,
                                                    const unsigned short* __restrict__ Bfrag,
                                                    unsigned short* __restrict__ C,
                                                    int M, int ntiles) {
    constexpr int NKS = KK / 32;      // total 32-k MFMA steps (16 / 8)
    constexpr int S   = KK / 128;     // super-steps per tile (4 / 2)
    __shared__ unsigned short As[2][64 * 128];   // 2 x 16KB

    int tid = threadIdx.x;
    int wave = tid >> 6, lane = tid & 63;
    int mrow = lane & 15, quad = lane >> 4;

    const unsigned short* Abf = (const unsigned short*)Avoid;
    const float*          Afp = (const float*)Avoid;

    bf16x8 bfr[NKS][2];
#pragma unroll
    for (int ks = 0; ks < NKS; ++ks)
#pragma unroll
        for (int jj = 0; jj < 2; ++jj)
            bfr[ks][jj] = *(const bf16x8*)(Bfrag +
                ((((size_t)wave * NKS + ks) * 2 + jj) * 64 + lane) * 8);

    int c  = tid & 15;                 // 16B chunk within 128-k slab
    int r0 = tid >> 4;                 // 0..31
    int cs0 = (c ^ (r0 & 7)) << 3;            // swizzled ushort offset, row r0
    int cs1 = (c ^ ((r0 + 32) & 7)) << 3;     // swizzled ushort offset, row r0+32

    float4 a0, a1, a2, a3;
    uint4  u0, u1;

    auto issue = [&](int t_, int s_) {
        int g0 = t_ * 64 + r0;       if (g0 >= M) g0 = M - 1;
        int g1 = t_ * 64 + r0 + 32;  if (g1 >= M) g1 = M - 1;
        if constexpr (ABF16) {
            u0 = *(const uint4*)(Abf + (size_t)g0 * KK + s_ * 128 + c * 8);
            u1 = *(const uint4*)(Abf + (size_t)g1 * KK + s_ * 128 + c * 8);
        } else {
            const float* p0 = Afp + (size_t)g0 * KK + s_ * 128 + c * 8;
            const float* p1 = Afp + (size_t)g1 * KK + s_ * 128 + c * 8;
            a0 = *(const float4*)p0; a1 = *(const float4*)(p0 + 4);
            a2 = *(const float4*)p1; a3 = *(const float4*)(p1 + 4);
        }
    };

    floatx4 acc[4][2];
#pragma unroll
    for (int i = 0; i < 4; ++i)
#pragma unroll
        for (int jj = 0; jj < 2; ++jj) acc[i][jj] = (floatx4){0.f, 0.f, 0.f, 0.f};

    int tile = blockIdx.x;
    if (tile < ntiles) issue(tile, 0);
    int cur = 0;

    for (; tile < ntiles; tile += gridDim.x) {
#pragma unroll
        for (int s = 0; s < S; ++s) {
            if constexpr (ABF16) {
                *(uint4*)&As[cur][r0 * 128 + cs0] = u0;
                *(uint4*)&As[cur][(r0 + 32) * 128 + cs1] = u1;
            } else {
                unsigned short h0[8] = {f2bf(a0.x), f2bf(a0.y), f2bf(a0.z), f2bf(a0.w),
                                        f2bf(a1.x), f2bf(a1.y), f2bf(a1.z), f2bf(a1.w)};
                unsigned short h1[8] = {f2bf(a2.x), f2bf(a2.y), f2bf(a2.z), f2bf(a2.w),
                                        f2bf(a3.x), f2bf(a3.y), f2bf(a3.z), f2bf(a3.w)};
                *(uint4*)&As[cur][r0 * 128 + cs0] = *(uint4*)h0;
                *(uint4*)&As[cur][(r0 + 32) * 128 + cs1] = *(uint4*)h1;
            }
            if (s + 1 < S) issue(tile, s + 1);
            else if (tile + (int)gridDim.x < ntiles) issue(tile + gridDim.x, 0);

            asm volatile("s_waitcnt lgkmcnt(0)" ::: "memory");
            __builtin_amdgcn_s_barrier();

#pragma unroll
            for (int ks = 0; ks < 4; ++ks) {
#pragma unroll
                for (int i = 0; i < 4; ++i) {
                    int row = i * 16 + mrow;
                    bf16x8 af = *(const bf16x8*)&As[cur][row * 128 +
                                    (((ks * 4 + quad) ^ (row & 7)) << 3)];
#pragma unroll
                    for (int jj = 0; jj < 2; ++jj)
                        acc[i][jj] = __builtin_amdgcn_mfma_f32_16x16x32_bf16(
                            af, bfr[s * 4 + ks][jj], acc[i][jj], 0, 0, 0);
                }
            }
            asm volatile("s_waitcnt lgkmcnt(0)" ::: "memory");
            __builtin_amdgcn_s_barrier();
            cur ^= 1;
        }
#pragma unroll
        for (int i = 0; i < 4; ++i)
#pragma unroll
            for (int jj = 0; jj < 2; ++jj) {
                int colo = wave * 32 + jj * 16 + mrow;
#pragma unroll
                for (int v = 0; v < 4; ++v) {
                    int row = tile * 64 + i * 16 + quad * 4 + v;
                    if (row < M) C[(size_t)row * HID_F + colo] = f2bf(acc[i][jj][v]);
                }
                acc[i][jj] = (floatx4){0.f, 0.f, 0.f, 0.f};
            }
    }
}

// ---------------- aggregation (gather, CSR), bf16 m, fp32 accumulate ----------------
// 4 rows per 256-thread block (one wave per row) — lifts the per-CU workgroup-slot
// cap that limited 64-thread blocks to ~70% occupancy. Batch-8 gather pipeline.

__global__ void agg_relu(const unsigned short* __restrict__ m, const int* __restrict__ row_ptr,
                         const int* __restrict__ col, const float* __restrict__ val,
                         const float* __restrict__ bias, unsigned short* __restrict__ hidden,
                         int N) {
    int wave = threadIdx.x >> 6, lane = threadIdx.x & 63;
    int i = blockIdx.x * 4 + wave;
    if (i >= N) return;
    int c0 = lane << 2;
    int p0 = __builtin_amdgcn_readfirstlane(row_ptr[i]);
    int p1 = __builtin_amdgcn_readfirstlane(row_ptr[i + 1]);
    float a0 = 0.f, a1 = 0.f, a2 = 0.f, a3 = 0.f;
    for (int p = p0; p < p1; p += 8) {
        int sj[8]; float wj[8];
#pragma unroll
        for (int j = 0; j < 8; ++j) {
            int q = p + j;
            bool ok = q < p1; if (!ok) q = p1 - 1;   // every row has >=1 edge (self-loop)
            sj[j] = col[q];
            wj[j] = ok ? val[q] : 0.f;
        }
        ushort4 u[8];
#pragma unroll
        for (int j = 0; j < 8; ++j)
            u[j] = *(const ushort4*)(m + (size_t)sj[j] * HID_F + c0);
#pragma unroll
        for (int j = 0; j < 8; ++j) {
            a0 = fmaf(bf2f(u[j].x), wj[j], a0);
            a1 = fmaf(bf2f(u[j].y), wj[j], a1);
            a2 = fmaf(bf2f(u[j].z), wj[j], a2);
            a3 = fmaf(bf2f(u[j].w), wj[j], a3);
        }
    }
    float4 b = *(const float4*)(bias + c0);
    a0 = fmaxf(a0 + b.x, 0.f); a1 = fmaxf(a1 + b.y, 0.f);
    a2 = fmaxf(a2 + b.z, 0.f); a3 = fmaxf(a3 + b.w, 0.f);
    ushort4 o = make_ushort4(f2bf(a0), f2bf(a1), f2bf(a2), f2bf(a3));
    *(ushort4*)(hidden + (size_t)i * HID_F + c0) = o;
}

__global__ void agg_out(const unsigned short* __restrict__ m, const int* __restrict__ row_ptr,
                        const int* __restrict__ col, const float* __restrict__ val,
                        const float* __restrict__ bmu, const float* __restrict__ blv,
                        float* __restrict__ out, int N) {
    int wave = threadIdx.x >> 6, lane = threadIdx.x & 63;
    int i = blockIdx.x * 4 + wave;
    if (i >= N) return;
    int c0 = lane << 2;
    int p0 = __builtin_amdgcn_readfirstlane(row_ptr[i]);
    int p1 = __builtin_amdgcn_readfirstlane(row_ptr[i + 1]);
    float a0 = 0.f, a1 = 0.f, a2 = 0.f, a3 = 0.f;
    for (int p = p0; p < p1; p += 8) {
        int sj[8]; float wj[8];
#pragma unroll
        for (int j = 0; j < 8; ++j) {
            int q = p + j;
            bool ok = q < p1; if (!ok) q = p1 - 1;
            sj[j] = col[q];
            wj[j] = ok ? val[q] : 0.f;
        }
        ushort4 u[8];
#pragma unroll
        for (int j = 0; j < 8; ++j)
            u[j] = *(const ushort4*)(m + (size_t)sj[j] * HID_F + c0);
#pragma unroll
        for (int j = 0; j < 8; ++j) {
            a0 = fmaf(bf2f(u[j].x), wj[j], a0);
            a1 = fmaf(bf2f(u[j].y), wj[j], a1);
            a2 = fmaf(bf2f(u[j].z), wj[j], a2);
            a3 = fmaf(bf2f(u[j].w), wj[j], a3);
        }
    }
    if (lane < 32) {
        float4 b = *(const float4*)(bmu + c0);
        float4 o = make_float4(a0 + b.x, a1 + b.y, a2 + b.z, a3 + b.w);
        *(float4*)(out + (size_t)i * LAT_F + c0) = o;
    } else {
        int c = c0 - 128;
        float4 b = *(const float4*)(blv + c);
        float4 o = make_float4(a0 + b.x, a1 + b.y, a2 + b.z, a3 + b.w);
        *(float4*)(out + (size_t)(N + i) * LAT_F + c) = o;
    }
}

// ---------------- launch ----------------

extern "C" void kernel_launch(void* const* d_in, const int* in_sizes, int n_in,
                              void* d_out, int out_size, void* d_ws, size_t ws_size,
                              hipStream_t stream) {
    const float* x    = (const float*)d_in[0];
    const int*   ei   = (const int*)d_in[1];
    const float* attr = (const float*)d_in[2];
    const float* W1   = (const float*)d_in[3];
    const float* b1   = (const float*)d_in[4];
    const float* Wmu  = (const float*)d_in[5];
    const float* bmu  = (const float*)d_in[6];
    const float* Wlv  = (const float*)d_in[7];
    const float* blv  = (const float*)d_in[8];
    float* out = (float*)d_out;

    const int N  = in_sizes[0] / IN_F;   // 50000
    const int E  = in_sizes[2];          // 800000
    const int EN = E + N;

    char* w = (char*)d_ws;
    size_t off = 0;
    auto carve = [&](size_t bytes) -> void* {
        void* p = w + off; off += (bytes + 255) & ~(size_t)255; return p;
    };
    unsigned long long* packed = (unsigned long long*)carve((size_t)N * 8);
    float*          dis       = (float*)carve((size_t)N * 4);
    int*            row_ptr   = (int*)  carve((size_t)(N + 1) * 4);
    int*            blockSums = (int*)  carve(64 * 4);
    int*            slot      = (int*)  carve((size_t)E * 4);
    int*            col       = (int*)  carve((size_t)EN * 4);
    float*          val       = (float*)carve((size_t)EN * 4);
    unsigned short* Bf1       = (unsigned short*)carve((size_t)HID_F * IN_F * 2);
    unsigned short* Bf2       = (unsigned short*)carve((size_t)HID_F * HID_F * 2);
    unsigned short* m         = (unsigned short*)carve((size_t)N * HID_F * 2);  // m1, reused as m2
    unsigned short* hidden    = (unsigned short*)carve((size_t)N * HID_F * 2);

    prep_all<<<(HID_F * IN_F + 255) / 256, 256, 0, stream>>>(W1, Wmu, Wlv, packed, Bf1, Bf2, N);

    edge_deg<<<(E + 255) / 256, 256, 0, stream>>>(ei, attr, packed, slot, E);

    int NB = (N + 1023) / 1024;
    scan_blocks<<<NB, 256, 0, stream>>>(packed, dis, row_ptr, blockSums, N);
    scan_sums<<<1, 64, 0, stream>>>(blockSums, NB);
    scan_add<<<NB, 256, 0, stream>>>(row_ptr, blockSums, N, EN);

    fill_csr<<<(EN + 255) / 256, 256, 0, stream>>>(ei, attr, slot, dis, row_ptr, col, val, E, N);

    int ntiles = (N + 63) / 64;
    int ggrid = ntiles < 512 ? ntiles : 512;
    // m1 = bf16(x) @ W1   [50000,512]x[512,256] -> bf16
    gemm_breg<false, IN_F><<<ggrid, 512, 0, stream>>>(x, Bf1, m, N, ntiles);
    // hidden = relu(A_hat * m1 + b1) -> bf16
    agg_relu<<<(N + 3) / 4, 256, 0, stream>>>(m, row_ptr, col, val, b1, hidden, N);
    // m2 = hidden @ [W_mu | W_lv]   [50000,256]x[256,256] -> bf16
    gemm_breg<true, HID_F><<<ggrid, 512, 0, stream>>>(hidden, Bf2, m, N, ntiles);
    // (mu|logvar) = A_hat * m2 + (b_mu|b_lv) -> fp32 d_out
    agg_out<<<(N + 3) / 4, 256, 0, stream>>>(m, row_ptr, col, val, bmu, blv, out, N);
}